// Round 2
// baseline (1413.990 us; speedup 1.0000x reference)
//
#include <hip/hip_runtime.h>
#include <math.h>

// Problem constants
constexpr int N_TOKENS = 8192;
constexpr int D_MODEL  = 4096;
constexpr int N_EXP    = 256;

// Split-K GEMM: 64 tokens x 256 experts per block, K split 4 ways.
constexpr int BM = 64;
constexpr int BK = 16;
constexpr int SPLITS = 4;
constexpr int KS = D_MODEL / SPLITS;   // 1024 per split
constexpr int NC = KS / BK;            // 64 chunks

constexpr int AS_STRIDE = BM + 4;      // 68 floats = 272 B (16B-aligned rows)
constexpr int BS_STRIDE = N_EXP + 4;   // 260 floats = 1040 B (16B-aligned rows)

// logits[n,e] += sum_{k in split} H[n,k] * W[e,k]
__global__ __launch_bounds__(256, 2) void gate_gemm(
    const float* __restrict__ H, const float* __restrict__ W,
    float* __restrict__ logits)
{
    __shared__ alignas(16) float As[2][BK][AS_STRIDE];
    __shared__ alignas(16) float Bs[2][BK][BS_STRIDE];

    const int t    = threadIdx.x;
    const int tx   = t & 31;           // expert group: experts tx*4..+3 and 128+tx*4..+3
    const int ty   = t >> 5;           // token group: tokens ty*8..+7
    const int tok0 = blockIdx.x * BM;
    const int k0   = blockIdx.y * KS;  // split's K range

    // A staging: 64 tok x 16 k = 256 float4, one per thread
    const int tokA = t >> 2;
    const int kqA  = t & 3;

    float4 pa;
    float4 pb[4];                      // B chunk: 256 exp x 16 k = 1024 float4 / 256 thr

    float acc[8][8];
    #pragma unroll
    for (int i = 0; i < 8; ++i)
        #pragma unroll
        for (int j = 0; j < 8; ++j) acc[i][j] = 0.0f;

    auto issue_loads = [&](int kc) {
        pa = *(const float4*)(H + (size_t)(tok0 + tokA) * D_MODEL + kc + kqA * 4);
        #pragma unroll
        for (int j = 0; j < 4; ++j) {
            const int flat = t + 256 * j;      // [0,1024)
            const int e    = flat >> 2;        // 0..255
            const int kq   = flat & 3;         // 0..3
            pb[j] = *(const float4*)(W + (size_t)e * D_MODEL + kc + kq * 4);
        }
    };

    auto write_lds = [&](int buf) {
        As[buf][kqA * 4 + 0][tokA] = pa.x;
        As[buf][kqA * 4 + 1][tokA] = pa.y;
        As[buf][kqA * 4 + 2][tokA] = pa.z;
        As[buf][kqA * 4 + 3][tokA] = pa.w;
        #pragma unroll
        for (int j = 0; j < 4; ++j) {
            const int flat = t + 256 * j;
            const int e    = flat >> 2;
            const int kq   = flat & 3;
            Bs[buf][kq * 4 + 0][e] = pb[j].x;
            Bs[buf][kq * 4 + 1][e] = pb[j].y;
            Bs[buf][kq * 4 + 2][e] = pb[j].z;
            Bs[buf][kq * 4 + 3][e] = pb[j].w;
        }
    };

    issue_loads(k0);
    write_lds(0);
    __syncthreads();

    for (int c = 0; c < NC; ++c) {
        const int buf = c & 1;
        if (c + 1 < NC) issue_loads(k0 + (c + 1) * BK);

        #pragma unroll
        for (int k = 0; k < BK; ++k) {
            const float4 a0 = *(const float4*)&As[buf][k][ty * 8];
            const float4 a1 = *(const float4*)&As[buf][k][ty * 8 + 4];
            const float4 b0 = *(const float4*)&Bs[buf][k][tx * 4];
            const float4 b1 = *(const float4*)&Bs[buf][k][128 + tx * 4];
            const float a[8] = {a0.x, a0.y, a0.z, a0.w, a1.x, a1.y, a1.z, a1.w};
            const float b[8] = {b0.x, b0.y, b0.z, b0.w, b1.x, b1.y, b1.z, b1.w};
            #pragma unroll
            for (int i = 0; i < 8; ++i)
                #pragma unroll
                for (int j = 0; j < 8; ++j)
                    acc[i][j] = fmaf(a[i], b[j], acc[i][j]);
        }

        if (c + 1 < NC) write_lds(buf ^ 1);
        __syncthreads();
    }

    // Epilogue: accumulate this split's partial into logits.
    #pragma unroll
    for (int i = 0; i < 8; ++i) {
        float* row = logits + (size_t)(tok0 + ty * 8 + i) * N_EXP;
        #pragma unroll
        for (int j = 0; j < 4; ++j) {
            atomicAdd(row + tx * 4 + j,       acc[i][j]);
            atomicAdd(row + 128 + tx * 4 + j, acc[i][4 + j]);
        }
    }
}

// One wave per token: coalesced float4 load of 256 logits, sigmoid, per-group
// (16 lanes = 64 experts) shuffle-butterfly top-2 with lower-index tie-break.
__global__ __launch_bounds__(256) void topk_kernel(
    const float* __restrict__ logits,
    float* __restrict__ out_idx, float* __restrict__ out_w)
{
    const int token = blockIdx.x * 4 + (threadIdx.x >> 6);
    const int lane  = threadIdx.x & 63;

    const float4 x = *(const float4*)(logits + (size_t)token * N_EXP + lane * 4);
    float s[4];
    s[0] = 1.0f / (1.0f + expf(-x.x));
    s[1] = 1.0f / (1.0f + expf(-x.y));
    s[2] = 1.0f / (1.0f + expf(-x.z));
    s[3] = 1.0f / (1.0f + expf(-x.w));

    // local top2 of this lane's 4 values (global expert indices lane*4+j)
    float v1 = -1.0f, v2 = -1.0f;
    int   i1 = 0,     i2 = 0;
    #pragma unroll
    for (int j = 0; j < 4; ++j) {
        const int idx = lane * 4 + j;
        if (s[j] > v1)      { v2 = v1; i2 = i1; v1 = s[j]; i1 = idx; }
        else if (s[j] > v2) { v2 = s[j]; i2 = idx; }
    }

    // butterfly merge across the 16 lanes of this group (offsets 1,2,4,8)
    #pragma unroll
    for (int off = 1; off < 16; off <<= 1) {
        const float ov1 = __shfl_xor(v1, off);
        const int   oi1 = __shfl_xor(i1, off);
        const float ov2 = __shfl_xor(v2, off);
        const int   oi2 = __shfl_xor(i2, off);
        // merge two sorted-2 lists; tie -> lower index first
        const bool o1_beats_m1 = (ov1 > v1) || (ov1 == v1 && oi1 < i1);
        if (o1_beats_m1) {
            const bool m1_beats_o2 = (v1 > ov2) || (v1 == ov2 && i1 < oi2);
            const float nv2 = m1_beats_o2 ? v1 : ov2;
            const int   ni2 = m1_beats_o2 ? i1 : oi2;
            v1 = ov1; i1 = oi1; v2 = nv2; i2 = ni2;
        } else {
            const bool o1_beats_m2 = (ov1 > v2) || (ov1 == v2 && oi1 < i2);
            v2 = o1_beats_m2 ? ov1 : v2;
            i2 = o1_beats_m2 ? oi1 : i2;
        }
    }

    // every lane now holds its group's top2; group g's result lives in lane g*16
    float sum = 0.0f;
    #pragma unroll
    for (int g = 0; g < 4; ++g)
        sum += __shfl(v1, g * 16) + __shfl(v2, g * 16);

    const int   src = ((lane >> 1) & 3) * 16;
    const float mv1 = __shfl(v1, src);
    const float mv2 = __shfl(v2, src);
    const int   mi1 = __shfl(i1, src);
    const int   mi2 = __shfl(i2, src);

    if (lane < 8) {
        const float myv = (lane & 1) ? mv2 : mv1;
        const int   myi = (lane & 1) ? mi2 : mi1;
        out_idx[(size_t)token * 8 + lane] = (float)myi;
        out_w  [(size_t)token * 8 + lane] = myv * (2.5f / (sum + 1e-10f));
    }
}

extern "C" void kernel_launch(void* const* d_in, const int* in_sizes, int n_in,
                              void* d_out, int out_size, void* d_ws, size_t ws_size,
                              hipStream_t stream) {
    const float* H = (const float*)d_in[0];   // hidden_states [8192, 4096]
    const float* W = (const float*)d_in[1];   // gate_w        [256, 4096]

    float* out      = (float*)d_out;
    float* out_idx  = out;                                   // 8192*8
    float* out_w    = out + (size_t)N_TOKENS * 8;            // 8192*8
    float* logits   = out + (size_t)N_TOKENS * 16;           // 8192*256

    hipMemsetAsync(logits, 0, (size_t)N_TOKENS * N_EXP * sizeof(float), stream);
    gate_gemm<<<dim3(N_TOKENS / BM, SPLITS), dim3(256), 0, stream>>>(H, W, logits);
    topk_kernel<<<dim3(N_TOKENS / 4), dim3(256), 0, stream>>>(logits, out_idx, out_w);
}

// Round 3
// 347.742 us; speedup vs baseline: 4.0662x; 4.0662x over previous
//
#include <hip/hip_runtime.h>
#include <math.h>

// Problem constants
constexpr int N_TOKENS = 8192;
constexpr int D_MODEL  = 4096;
constexpr int N_EXP    = 256;

// bf16-split MFMA GEMM tiling
constexpr int BM     = 64;                 // tokens per block
constexpr int BK     = 32;                 // K per chunk == MFMA K
constexpr int SPLITS = 4;
constexpr int KS     = D_MODEL / SPLITS;   // 1024
constexpr int NCHUNK = KS / BK;            // 32

constexpr int AS = 40;   // LDS row stride in ushort (32 + 8 pad) -> conflict-free b128 frag reads

constexpr size_t W16_ELEMS = (size_t)N_EXP * D_MODEL;               // 1M per plane
constexpr size_t P_ELEMS   = (size_t)SPLITS * N_TOKENS * N_EXP;     // 8.4M
constexpr size_t WS_NEED   = 2 * W16_ELEMS * sizeof(unsigned short) // Whi+Wlo: 4 MB
                           + P_ELEMS * sizeof(float);               // partials: 33.5 MB

typedef __attribute__((ext_vector_type(8))) short short8;
typedef __attribute__((ext_vector_type(4))) float f32x4;

static __device__ __forceinline__ unsigned short f2bf(float x) {
    union { float f; unsigned u; } v; v.f = x;
    unsigned r = v.u + 0x7fffu + ((v.u >> 16) & 1u);   // RNE
    return (unsigned short)(r >> 16);
}
static __device__ __forceinline__ float bf2f(unsigned short s) {
    union { unsigned u; float f; } v; v.u = ((unsigned)s) << 16;
    return v.f;
}

// ---------------- W pre-conversion: fp32 -> bf16 hi/lo planes ----------------
__global__ __launch_bounds__(256) void convert_w(
    const float* __restrict__ W,
    unsigned short* __restrict__ Whi, unsigned short* __restrict__ Wlo)
{
    const size_t base = ((size_t)blockIdx.x * 256 + threadIdx.x) * 8;
    const float4 x0 = *(const float4*)(W + base);
    const float4 x1 = *(const float4*)(W + base + 4);
    const float xs[8] = {x0.x, x0.y, x0.z, x0.w, x1.x, x1.y, x1.z, x1.w};
    short8 vh, vl;
    #pragma unroll
    for (int j = 0; j < 8; ++j) {
        const unsigned short h = f2bf(xs[j]);
        const unsigned short l = f2bf(xs[j] - bf2f(h));
        vh[j] = (short)h;
        vl[j] = (short)l;
    }
    *(short8*)(Whi + base) = vh;
    *(short8*)(Wlo + base) = vl;
}

// ---------------- Split-K bf16x3 MFMA GEMM ----------------
// P[s][tok][e] = sum_{k in split s} H[tok][k] * W[e][k]
__global__ __launch_bounds__(256, 2) void gate_gemm_bf16(
    const float* __restrict__ H,
    const unsigned short* __restrict__ Whi, const unsigned short* __restrict__ Wlo,
    float* __restrict__ P)
{
    __shared__ unsigned short Ahi[BM][AS],    Alo[BM][AS];     // 10.0 KB
    __shared__ unsigned short Bhi[N_EXP][AS], Blo[N_EXP][AS];  // 40.0 KB

    const int t      = threadIdx.x;
    const int L      = t & 63;
    const int w      = t >> 6;       // wave id: experts [w*64, w*64+64)
    const int lane16 = L & 15;
    const int quad   = L >> 4;

    const int m0 = blockIdx.x * BM;
    const int s  = blockIdx.y;
    const int k0 = s * KS;

    // A staging: thread t loads H[m0 + (t>>2)][k + (t&3)*8 .. +7] (2 float4)
    const int tokA = t >> 2, kgA = t & 3;

    float4 pa0, pa1;
    int4 pbh[4], pbl[4];   // B chunk: 256 exp x 4 granules of 8 ushort, per plane

    f32x4 acc[4][4];
    #pragma unroll
    for (int mi = 0; mi < 4; ++mi)
        #pragma unroll
        for (int ni = 0; ni < 4; ++ni) acc[mi][ni] = (f32x4)0.0f;

    auto issue = [&](int kc) {
        const float* hp = H + (size_t)(m0 + tokA) * D_MODEL + kc + kgA * 8;
        pa0 = *(const float4*)hp;
        pa1 = *(const float4*)(hp + 4);
        #pragma unroll
        for (int r = 0; r < 4; ++r) {
            const int flat = t + 256 * r;          // [0,1024)
            const int e    = flat >> 2;            // 0..255
            const int kg   = flat & 3;             // 0..3
            const size_t off = (size_t)e * D_MODEL + kc + kg * 8;
            pbh[r] = *(const int4*)(Whi + off);
            pbl[r] = *(const int4*)(Wlo + off);
        }
    };

    auto commit = [&]() {
        const float xs[8] = {pa0.x, pa0.y, pa0.z, pa0.w, pa1.x, pa1.y, pa1.z, pa1.w};
        short8 vh, vl;
        #pragma unroll
        for (int j = 0; j < 8; ++j) {
            const unsigned short h = f2bf(xs[j]);
            vh[j] = (short)h;
            vl[j] = (short)f2bf(xs[j] - bf2f(h));
        }
        *(short8*)&Ahi[tokA][kgA * 8] = vh;
        *(short8*)&Alo[tokA][kgA * 8] = vl;
        #pragma unroll
        for (int r = 0; r < 4; ++r) {
            const int flat = t + 256 * r;
            const int e    = flat >> 2;
            const int kg   = flat & 3;
            *(int4*)&Bhi[e][kg * 8] = pbh[r];
            *(int4*)&Blo[e][kg * 8] = pbl[r];
        }
    };

    issue(k0);
    for (int c = 0; c < NCHUNK; ++c) {
        __syncthreads();                 // prior chunk's MFMA reads done; LDS reusable
        commit();
        if (c + 1 < NCHUNK) issue(k0 + (c + 1) * BK);  // in flight across the MFMAs
        __syncthreads();                 // LDS ready

        short8 ah[4], al[4];
        #pragma unroll
        for (int mi = 0; mi < 4; ++mi) {
            ah[mi] = *(const short8*)&Ahi[mi * 16 + lane16][quad * 8];
            al[mi] = *(const short8*)&Alo[mi * 16 + lane16][quad * 8];
        }
        #pragma unroll
        for (int ni = 0; ni < 4; ++ni) {
            const int e = w * 64 + ni * 16 + lane16;
            const short8 bh = *(const short8*)&Bhi[e][quad * 8];
            const short8 bl = *(const short8*)&Blo[e][quad * 8];
            #pragma unroll
            for (int mi = 0; mi < 4; ++mi) {
                acc[mi][ni] = __builtin_amdgcn_mfma_f32_16x16x32_bf16(ah[mi], bh, acc[mi][ni], 0, 0, 0);
                acc[mi][ni] = __builtin_amdgcn_mfma_f32_16x16x32_bf16(ah[mi], bl, acc[mi][ni], 0, 0, 0);
                acc[mi][ni] = __builtin_amdgcn_mfma_f32_16x16x32_bf16(al[mi], bh, acc[mi][ni], 0, 0, 0);
            }
        }
    }

    // Epilogue: C/D layout col=lane&15 (expert), row=quad*4+r (token)
    float* Pb = P + (size_t)s * N_TOKENS * N_EXP;
    #pragma unroll
    for (int mi = 0; mi < 4; ++mi)
        #pragma unroll
        for (int r = 0; r < 4; ++r) {
            const int tok = m0 + mi * 16 + quad * 4 + r;
            float* row = Pb + (size_t)tok * N_EXP + w * 64;
            #pragma unroll
            for (int ni = 0; ni < 4; ++ni)
                row[ni * 16 + lane16] = acc[mi][ni][r];
        }
}

// ---------------- fused split-reduce + sigmoid + group-top2 + outputs ----------------
__global__ __launch_bounds__(256) void reduce_topk(
    const float* __restrict__ P, float* __restrict__ logits,
    float* __restrict__ out_idx, float* __restrict__ out_w)
{
    const int token = blockIdx.x * 4 + (threadIdx.x >> 6);
    const int lane  = threadIdx.x & 63;
    const size_t off    = (size_t)token * N_EXP + lane * 4;
    const size_t stride = (size_t)N_TOKENS * N_EXP;

    float4 x = *(const float4*)(P + off);
    #pragma unroll
    for (int sp = 1; sp < SPLITS; ++sp) {
        const float4 y = *(const float4*)(P + sp * stride + off);
        x.x += y.x; x.y += y.y; x.z += y.z; x.w += y.w;
    }
    *(float4*)(logits + off) = x;

    float sc[4];
    sc[0] = 1.0f / (1.0f + expf(-x.x));
    sc[1] = 1.0f / (1.0f + expf(-x.y));
    sc[2] = 1.0f / (1.0f + expf(-x.z));
    sc[3] = 1.0f / (1.0f + expf(-x.w));

    float v1 = -1.0f, v2 = -1.0f;
    int   i1 = 0,     i2 = 0;
    #pragma unroll
    for (int j = 0; j < 4; ++j) {
        const int idx = lane * 4 + j;
        if (sc[j] > v1)      { v2 = v1; i2 = i1; v1 = sc[j]; i1 = idx; }
        else if (sc[j] > v2) { v2 = sc[j]; i2 = idx; }
    }

    // butterfly merge across the 16 lanes of each group (64 experts/group)
    #pragma unroll
    for (int offx = 1; offx < 16; offx <<= 1) {
        const float ov1 = __shfl_xor(v1, offx);
        const int   oi1 = __shfl_xor(i1, offx);
        const float ov2 = __shfl_xor(v2, offx);
        const int   oi2 = __shfl_xor(i2, offx);
        const bool o1_beats_m1 = (ov1 > v1) || (ov1 == v1 && oi1 < i1);
        if (o1_beats_m1) {
            const bool m1_beats_o2 = (v1 > ov2) || (v1 == ov2 && i1 < oi2);
            const float nv2 = m1_beats_o2 ? v1 : ov2;
            const int   ni2 = m1_beats_o2 ? i1 : oi2;
            v1 = ov1; i1 = oi1; v2 = nv2; i2 = ni2;
        } else {
            const bool o1_beats_m2 = (ov1 > v2) || (ov1 == v2 && oi1 < i2);
            v2 = o1_beats_m2 ? ov1 : v2;
            i2 = o1_beats_m2 ? oi1 : i2;
        }
    }

    float sum = 0.0f;
    #pragma unroll
    for (int g = 0; g < 4; ++g)
        sum += __shfl(v1, g * 16) + __shfl(v2, g * 16);

    const int   src = ((lane >> 1) & 3) * 16;
    const float mv1 = __shfl(v1, src);
    const float mv2 = __shfl(v2, src);
    const int   mi1 = __shfl(i1, src);
    const int   mi2 = __shfl(i2, src);

    if (lane < 8) {
        const float myv = (lane & 1) ? mv2 : mv1;
        const int   myi = (lane & 1) ? mi2 : mi1;
        out_idx[(size_t)token * 8 + lane] = (float)myi;
        out_w  [(size_t)token * 8 + lane] = myv * (2.5f / (sum + 1e-10f));
    }
}

// ---------------- fallback (ws too small): round-1 fp32 path ----------------
constexpr int FBM = 32;
constexpr int FBK = 16;
constexpr int FNC = D_MODEL / FBK;

__global__ __launch_bounds__(256) void gate_gemm_f32(
    const float* __restrict__ H, const float* __restrict__ W,
    float* __restrict__ logits)
{
    __shared__ float As[2][FBK][FBM + 4];
    __shared__ float Bs[2][FBK][N_EXP + 1];

    const int t    = threadIdx.x;
    const int tx   = t & 31;
    const int ty   = t >> 5;
    const int tok0 = blockIdx.x * FBM;
    const int tokA = t >> 2;
    const int kqA  = t & 3;

    float4 pa;
    float4 pb[4];
    float acc[4][8];
    #pragma unroll
    for (int i = 0; i < 4; ++i)
        #pragma unroll
        for (int j = 0; j < 8; ++j) acc[i][j] = 0.0f;

    auto issue_loads = [&](int kc) {
        if (t < 128)
            pa = *(const float4*)(H + (size_t)(tok0 + tokA) * D_MODEL + kc + kqA * 4);
        #pragma unroll
        for (int j = 0; j < 4; ++j) {
            const int flat = t + 256 * j;
            const int e    = flat >> 2;
            const int kq   = flat & 3;
            pb[j] = *(const float4*)(W + (size_t)e * D_MODEL + kc + kq * 4);
        }
    };
    auto write_lds = [&](int buf) {
        if (t < 128) {
            As[buf][kqA * 4 + 0][tokA] = pa.x;
            As[buf][kqA * 4 + 1][tokA] = pa.y;
            As[buf][kqA * 4 + 2][tokA] = pa.z;
            As[buf][kqA * 4 + 3][tokA] = pa.w;
        }
        #pragma unroll
        for (int j = 0; j < 4; ++j) {
            const int flat = t + 256 * j;
            const int e    = flat >> 2;
            const int kq   = flat & 3;
            Bs[buf][kq * 4 + 0][e] = pb[j].x;
            Bs[buf][kq * 4 + 1][e] = pb[j].y;
            Bs[buf][kq * 4 + 2][e] = pb[j].z;
            Bs[buf][kq * 4 + 3][e] = pb[j].w;
        }
    };

    issue_loads(0);
    write_lds(0);
    __syncthreads();
    for (int c = 0; c < FNC; ++c) {
        const int buf = c & 1;
        if (c + 1 < FNC) issue_loads((c + 1) * FBK);
        #pragma unroll
        for (int k = 0; k < FBK; ++k) {
            const float4 av = *(const float4*)&As[buf][k][ty * 4];
            const float a[4] = {av.x, av.y, av.z, av.w};
            float b[8];
            #pragma unroll
            for (int j = 0; j < 8; ++j) b[j] = Bs[buf][k][tx + 32 * j];
            #pragma unroll
            for (int i = 0; i < 4; ++i)
                #pragma unroll
                for (int j = 0; j < 8; ++j)
                    acc[i][j] = fmaf(a[i], b[j], acc[i][j]);
        }
        if (c + 1 < FNC) write_lds(buf ^ 1);
        __syncthreads();
    }
    #pragma unroll
    for (int i = 0; i < 4; ++i) {
        const size_t row = (size_t)(tok0 + ty * 4 + i) * N_EXP;
        #pragma unroll
        for (int j = 0; j < 8; ++j)
            logits[row + tx + 32 * j] = acc[i][j];
    }
}

__global__ __launch_bounds__(256) void topk_only(
    const float* __restrict__ logits,
    float* __restrict__ out_idx, float* __restrict__ out_w)
{
    const int token = blockIdx.x * 4 + (threadIdx.x >> 6);
    const int lane  = threadIdx.x & 63;
    const float4 x = *(const float4*)(logits + (size_t)token * N_EXP + lane * 4);
    float sc[4];
    sc[0] = 1.0f / (1.0f + expf(-x.x));
    sc[1] = 1.0f / (1.0f + expf(-x.y));
    sc[2] = 1.0f / (1.0f + expf(-x.z));
    sc[3] = 1.0f / (1.0f + expf(-x.w));
    float v1 = -1.0f, v2 = -1.0f;
    int   i1 = 0,     i2 = 0;
    #pragma unroll
    for (int j = 0; j < 4; ++j) {
        const int idx = lane * 4 + j;
        if (sc[j] > v1)      { v2 = v1; i2 = i1; v1 = sc[j]; i1 = idx; }
        else if (sc[j] > v2) { v2 = sc[j]; i2 = idx; }
    }
    #pragma unroll
    for (int offx = 1; offx < 16; offx <<= 1) {
        const float ov1 = __shfl_xor(v1, offx);
        const int   oi1 = __shfl_xor(i1, offx);
        const float ov2 = __shfl_xor(v2, offx);
        const int   oi2 = __shfl_xor(i2, offx);
        const bool o1_beats_m1 = (ov1 > v1) || (ov1 == v1 && oi1 < i1);
        if (o1_beats_m1) {
            const bool m1_beats_o2 = (v1 > ov2) || (v1 == ov2 && i1 < oi2);
            const float nv2 = m1_beats_o2 ? v1 : ov2;
            const int   ni2 = m1_beats_o2 ? i1 : oi2;
            v1 = ov1; i1 = oi1; v2 = nv2; i2 = ni2;
        } else {
            const bool o1_beats_m2 = (ov1 > v2) || (ov1 == v2 && oi1 < i2);
            v2 = o1_beats_m2 ? ov1 : v2;
            i2 = o1_beats_m2 ? oi1 : i2;
        }
    }
    float sum = 0.0f;
    #pragma unroll
    for (int g = 0; g < 4; ++g)
        sum += __shfl(v1, g * 16) + __shfl(v2, g * 16);
    const int   src = ((lane >> 1) & 3) * 16;
    const float mv1 = __shfl(v1, src);
    const float mv2 = __shfl(v2, src);
    const int   mi1 = __shfl(i1, src);
    const int   mi2 = __shfl(i2, src);
    if (lane < 8) {
        const float myv = (lane & 1) ? mv2 : mv1;
        const int   myi = (lane & 1) ? mi2 : mi1;
        out_idx[(size_t)token * 8 + lane] = (float)myi;
        out_w  [(size_t)token * 8 + lane] = myv * (2.5f / (sum + 1e-10f));
    }
}

extern "C" void kernel_launch(void* const* d_in, const int* in_sizes, int n_in,
                              void* d_out, int out_size, void* d_ws, size_t ws_size,
                              hipStream_t stream) {
    const float* H = (const float*)d_in[0];   // hidden_states [8192, 4096]
    const float* W = (const float*)d_in[1];   // gate_w        [256, 4096]

    float* out     = (float*)d_out;
    float* out_idx = out;                           // 8192*8
    float* out_w   = out + (size_t)N_TOKENS * 8;    // 8192*8
    float* logits  = out + (size_t)N_TOKENS * 16;   // 8192*256

    if (ws_size >= WS_NEED) {
        unsigned short* Whi = (unsigned short*)d_ws;
        unsigned short* Wlo = Whi + W16_ELEMS;
        float* P = (float*)(Wlo + W16_ELEMS);

        convert_w<<<dim3(W16_ELEMS / (256 * 8)), dim3(256), 0, stream>>>(W, Whi, Wlo);
        gate_gemm_bf16<<<dim3(N_TOKENS / BM, SPLITS), dim3(256), 0, stream>>>(H, Whi, Wlo, P);
        reduce_topk<<<dim3(N_TOKENS / 4), dim3(256), 0, stream>>>(P, logits, out_idx, out_w);
    } else {
        gate_gemm_f32<<<dim3(N_TOKENS / FBM), dim3(256), 0, stream>>>(H, W, logits);
        topk_only<<<dim3(N_TOKENS / 4), dim3(256), 0, stream>>>(logits, out_idx, out_w);
    }
}

// Round 4
// 290.830 us; speedup vs baseline: 4.8619x; 1.1957x over previous
//
#include <hip/hip_runtime.h>
#include <math.h>

// Problem constants
constexpr int N_TOKENS = 8192;
constexpr int D_MODEL  = 4096;
constexpr int N_EXP    = 256;

// Fused one-shot GEMM: 32 tokens x 256 experts per block, no split-K.
constexpr int BM = 32;              // tokens per block
constexpr int BK = 32;              // K per chunk (= MFMA K)
constexpr int NC = D_MODEL / BK;    // 128 chunks

// ws B layout: [chunk c][plane hi/lo][256 exp x 32 k, XOR-swizzled granules]
constexpr int WPL = N_EXP * BK;     // 8192 ushorts per plane (16 KB)
constexpr int WCH = 2 * WPL;        // 16384 ushorts per chunk (32 KB)

// LDS stage layout (ushort units): Bhi | Blo | Ahi | Alo
constexpr int SB_HI = 0;
constexpr int SB_LO = 8192;
constexpr int SA_HI = 16384;
constexpr int SA_LO = 17408;
constexpr int STAGE = 18432;        // 36 KB per stage; 2 stages = 72 KB dynamic LDS
constexpr size_t LDS_BYTES = 2 * STAGE * sizeof(unsigned short);

constexpr size_t WS_NEED = (size_t)NC * WCH * sizeof(unsigned short);  // 4 MB

typedef __attribute__((ext_vector_type(8))) short short8;
typedef __attribute__((ext_vector_type(4))) short short4v;
typedef __attribute__((ext_vector_type(4))) float f32x4;
typedef unsigned int u32;
typedef const __attribute__((address_space(1))) u32* gas_ptr;
typedef __attribute__((address_space(3))) u32* las_ptr;

static __device__ __forceinline__ unsigned short f2bf(float x) {
    union { float f; unsigned u; } v; v.f = x;
    unsigned r = v.u + 0x7fffu + ((v.u >> 16) & 1u);   // RNE
    return (unsigned short)(r >> 16);
}
static __device__ __forceinline__ float bf2f(unsigned short s) {
    union { unsigned u; float f; } v; v.u = ((unsigned)s) << 16;
    return v.f;
}

// ---- W fp32 -> bf16 hi/lo, chunk-major + XOR-swizzled for global_load_lds ----
// Writer is perfectly linear in ws; the granule permutation is applied on the
// *read side* of W (same cache lines, quad-permuted) so ws == LDS image.
__global__ __launch_bounds__(256) void convert_w(
    const float* __restrict__ W, unsigned short* __restrict__ wsB)
{
    const int c    = blockIdx.x >> 2;           // chunk
    const int q    = blockIdx.x & 3;            // expert quarter
    const int t    = threadIdx.x;
    const int e    = q * 64 + (t >> 2);
    const int slot = t & 3;                     // physical 16B granule in row
    const int kq   = slot ^ ((e >> 1) & 3);     // logical k-granule (8 ushorts)

    const float* src = W + (size_t)e * D_MODEL + c * BK + kq * 8;
    const float4 x0 = *(const float4*)src;
    const float4 x1 = *(const float4*)(src + 4);
    const float xs[8] = {x0.x, x0.y, x0.z, x0.w, x1.x, x1.y, x1.z, x1.w};
    short8 vh, vl;
    #pragma unroll
    for (int j = 0; j < 8; ++j) {
        const unsigned short h = f2bf(xs[j]);
        vh[j] = (short)h;
        vl[j] = (short)f2bf(xs[j] - bf2f(h));
    }
    unsigned short* dst = wsB + (size_t)c * WCH + e * 32 + slot * 8;
    *(short8*)dst         = vh;
    *(short8*)(dst + WPL) = vl;
}

// ---- fused GEMM (bf16x3) + sigmoid + group-top2 + coalesced logits ----
__global__ __launch_bounds__(256, 1) void gate_fused(
    const float* __restrict__ H, const unsigned short* __restrict__ wsB,
    float* __restrict__ logits, float* __restrict__ out_idx, float* __restrict__ out_w)
{
    extern __shared__ unsigned short lds[];

    const int t      = threadIdx.x;
    const int L      = t & 63;
    const int w      = t >> 6;          // wave: experts [w*64, w*64+64)
    const int lane16 = L & 15;
    const int g4     = L >> 4;          // k-granule for frag reads
    const int tok0   = blockIdx.x * BM;

    // A staging map: thread t -> (token t>>3, granule-of-4-floats t&7)
    const int tokA = t >> 3;
    const int kgA  = t & 7;
    const int aoff = tokA * 32 + (((kgA >> 1) ^ ((tokA >> 1) & 3)) << 3) + ((kgA & 1) << 2);
    const float* hrow = H + (size_t)(tok0 + tokA) * D_MODEL + kgA * 4;

    f32x4 acc[2][4];
    #pragma unroll
    for (int mi = 0; mi < 2; ++mi)
        #pragma unroll
        for (int ni = 0; ni < 4; ++ni) acc[mi][ni] = (f32x4)0.0f;

    auto dmaB = [&](int c, int sb) {
        const unsigned short* src = wsB + (size_t)c * WCH;
        #pragma unroll
        for (int p = 0; p < 2; ++p)
            #pragma unroll
            for (int i = 0; i < 4; ++i) {
                const int o = p * WPL + (w * 4 + i) * 512;   // ushort offset
                __builtin_amdgcn_global_load_lds(
                    (gas_ptr)(const void*)(src + o + L * 8),
                    (las_ptr)(void*)(lds + sb + o), 16, 0, 0);
            }
    };

    auto commitA = [&](const float4& v, int sb) {
        const float xs[4] = {v.x, v.y, v.z, v.w};
        short4v hi, lo;
        #pragma unroll
        for (int j = 0; j < 4; ++j) {
            const unsigned short h = f2bf(xs[j]);
            hi[j] = (short)h;
            lo[j] = (short)f2bf(xs[j] - bf2f(h));
        }
        *(short4v*)(lds + sb + SA_HI + aoff) = hi;
        *(short4v*)(lds + sb + SA_LO + aoff) = lo;
    };

    auto compute = [&](int sb) {
        const unsigned short* Bh = lds + sb + SB_HI;
        const unsigned short* Bl = lds + sb + SB_LO;
        const unsigned short* Ah = lds + sb + SA_HI;
        const unsigned short* Al = lds + sb + SA_LO;
        short8 ah[2], al[2];
        #pragma unroll
        for (int mi = 0; mi < 2; ++mi) {
            const int row = mi * 16 + lane16;
            const int off = row * 32 + ((g4 ^ ((row >> 1) & 3)) << 3);
            ah[mi] = *(const short8*)(Ah + off);
            al[mi] = *(const short8*)(Al + off);
        }
        #pragma unroll
        for (int ni = 0; ni < 4; ++ni) {
            const int e   = w * 64 + ni * 16 + lane16;
            const int off = e * 32 + ((g4 ^ ((e >> 1) & 3)) << 3);
            const short8 bh = *(const short8*)(Bh + off);
            const short8 bl = *(const short8*)(Bl + off);
            #pragma unroll
            for (int mi = 0; mi < 2; ++mi) {
                acc[mi][ni] = __builtin_amdgcn_mfma_f32_16x16x32_bf16(ah[mi], bh, acc[mi][ni], 0, 0, 0);
                acc[mi][ni] = __builtin_amdgcn_mfma_f32_16x16x32_bf16(ah[mi], bl, acc[mi][ni], 0, 0, 0);
                acc[mi][ni] = __builtin_amdgcn_mfma_f32_16x16x32_bf16(al[mi], bh, acc[mi][ni], 0, 0, 0);
            }
        }
    };

    // Prologue: A(0), A(1) in regs; B(0) streaming; A(0) committed.
    float4 pa_cur  = *(const float4*)(hrow);
    float4 pa_next = *(const float4*)(hrow + BK);
    dmaB(0, 0);
    commitA(pa_cur, 0);
    __syncthreads();                    // drains B(0) DMA + A(0) writes

    for (int c = 0; c < NC; ++c) {
        const int sb  = (c & 1) ? STAGE : 0;
        const int sbn = STAGE - sb;
        float4 pa_far;
        if (c + 2 < NC) pa_far = *(const float4*)(hrow + (size_t)(c + 2) * BK);
        if (c + 1 < NC) dmaB(c + 1, sbn);        // overlaps compute below
        compute(sb);
        if (c + 1 < NC) commitA(pa_next, sbn);   // A(c+1) loaded last iter
        pa_next = pa_far;
        __syncthreads();
    }

    // ---- epilogue: LDS-transpose bounce, coalesced logits, fused topk ----
    float* Lt = (float*)lds;            // [32][256] fp32 = 32 KB (aliases stage0)
    #pragma unroll
    for (int mi = 0; mi < 2; ++mi)
        #pragma unroll
        for (int ni = 0; ni < 4; ++ni)
            #pragma unroll
            for (int r = 0; r < 4; ++r) {
                const int tok = mi * 16 + g4 * 4 + r;       // C/D: row = quad*4+reg
                const int col = w * 64 + ni * 16 + lane16;  // C/D: col = lane&15
                Lt[tok * N_EXP + col] = acc[mi][ni][r];
            }
    __syncthreads();

    // coalesced logits store: 8192 floats = 2048 float4, 8 per thread
    float4*       Lg  = (float4*)(logits + (size_t)tok0 * N_EXP);
    const float4* Lt4 = (const float4*)Lt;
    #pragma unroll
    for (int i = 0; i < 8; ++i) Lg[i * 256 + t] = Lt4[i * 256 + t];

    // topk: wave w handles local tokens w*8 .. w*8+7
    for (int it = 0; it < 8; ++it) {
        const int tk = w * 8 + it;
        const float4 x = ((const float4*)(Lt + tk * N_EXP))[L];
        float sc[4];
        sc[0] = 1.0f / (1.0f + expf(-x.x));
        sc[1] = 1.0f / (1.0f + expf(-x.y));
        sc[2] = 1.0f / (1.0f + expf(-x.z));
        sc[3] = 1.0f / (1.0f + expf(-x.w));

        float v1 = -1.0f, v2 = -1.0f;
        int   i1 = 0,     i2 = 0;
        #pragma unroll
        for (int j = 0; j < 4; ++j) {
            const int idx = L * 4 + j;
            if (sc[j] > v1)      { v2 = v1; i2 = i1; v1 = sc[j]; i1 = idx; }
            else if (sc[j] > v2) { v2 = sc[j]; i2 = idx; }
        }
        // butterfly merge across each 16-lane group (= 64-expert group)
        #pragma unroll
        for (int offx = 1; offx < 16; offx <<= 1) {
            const float ov1 = __shfl_xor(v1, offx);
            const int   oi1 = __shfl_xor(i1, offx);
            const float ov2 = __shfl_xor(v2, offx);
            const int   oi2 = __shfl_xor(i2, offx);
            const bool o1_beats_m1 = (ov1 > v1) || (ov1 == v1 && oi1 < i1);
            if (o1_beats_m1) {
                const bool m1_beats_o2 = (v1 > ov2) || (v1 == ov2 && i1 < oi2);
                const float nv2 = m1_beats_o2 ? v1 : ov2;
                const int   ni2 = m1_beats_o2 ? i1 : oi2;
                v1 = ov1; i1 = oi1; v2 = nv2; i2 = ni2;
            } else {
                const bool o1_beats_m2 = (ov1 > v2) || (ov1 == v2 && oi1 < i2);
                v2 = o1_beats_m2 ? ov1 : v2;
                i2 = o1_beats_m2 ? oi1 : i2;
            }
        }
        float sum = 0.0f;
        #pragma unroll
        for (int g = 0; g < 4; ++g)
            sum += __shfl(v1, g * 16) + __shfl(v2, g * 16);
        const int   src = ((L >> 1) & 3) * 16;
        const float mv1 = __shfl(v1, src);
        const float mv2 = __shfl(v2, src);
        const int   mi1 = __shfl(i1, src);
        const int   mi2 = __shfl(i2, src);
        if (L < 8) {
            const float myv = (L & 1) ? mv2 : mv1;
            const int   myi = (L & 1) ? mi2 : mi1;
            out_idx[(size_t)(tok0 + tk) * 8 + L] = (float)myi;
            out_w  [(size_t)(tok0 + tk) * 8 + L] = myv * (2.5f / (sum + 1e-10f));
        }
    }
}

// ---------------- fallback (ws too small): fp32 VALU path ----------------
constexpr int FBM = 32;
constexpr int FBK = 16;
constexpr int FNC = D_MODEL / FBK;

__global__ __launch_bounds__(256) void gate_gemm_f32(
    const float* __restrict__ H, const float* __restrict__ W,
    float* __restrict__ logits)
{
    __shared__ float As[2][FBK][FBM + 4];
    __shared__ float Bs[2][FBK][N_EXP + 1];
    const int t = threadIdx.x, tx = t & 31, ty = t >> 5;
    const int tok0 = blockIdx.x * FBM, tokA = t >> 2, kqA = t & 3;
    float4 pa, pb[4];
    float acc[4][8];
    #pragma unroll
    for (int i = 0; i < 4; ++i)
        #pragma unroll
        for (int j = 0; j < 8; ++j) acc[i][j] = 0.0f;
    auto issue_loads = [&](int kc) {
        if (t < 128) pa = *(const float4*)(H + (size_t)(tok0 + tokA) * D_MODEL + kc + kqA * 4);
        #pragma unroll
        for (int j = 0; j < 4; ++j) {
            const int flat = t + 256 * j, e = flat >> 2, kq = flat & 3;
            pb[j] = *(const float4*)(W + (size_t)e * D_MODEL + kc + kq * 4);
        }
    };
    auto write_lds = [&](int buf) {
        if (t < 128) {
            As[buf][kqA * 4 + 0][tokA] = pa.x; As[buf][kqA * 4 + 1][tokA] = pa.y;
            As[buf][kqA * 4 + 2][tokA] = pa.z; As[buf][kqA * 4 + 3][tokA] = pa.w;
        }
        #pragma unroll
        for (int j = 0; j < 4; ++j) {
            const int flat = t + 256 * j, e = flat >> 2, kq = flat & 3;
            Bs[buf][kq * 4 + 0][e] = pb[j].x; Bs[buf][kq * 4 + 1][e] = pb[j].y;
            Bs[buf][kq * 4 + 2][e] = pb[j].z; Bs[buf][kq * 4 + 3][e] = pb[j].w;
        }
    };
    issue_loads(0); write_lds(0); __syncthreads();
    for (int c = 0; c < FNC; ++c) {
        const int buf = c & 1;
        if (c + 1 < FNC) issue_loads((c + 1) * FBK);
        #pragma unroll
        for (int k = 0; k < FBK; ++k) {
            const float4 av = *(const float4*)&As[buf][k][ty * 4];
            const float a[4] = {av.x, av.y, av.z, av.w};
            float b[8];
            #pragma unroll
            for (int j = 0; j < 8; ++j) b[j] = Bs[buf][k][tx + 32 * j];
            #pragma unroll
            for (int i = 0; i < 4; ++i)
                #pragma unroll
                for (int j = 0; j < 8; ++j) acc[i][j] = fmaf(a[i], b[j], acc[i][j]);
        }
        if (c + 1 < FNC) write_lds(buf ^ 1);
        __syncthreads();
    }
    #pragma unroll
    for (int i = 0; i < 4; ++i) {
        const size_t row = (size_t)(tok0 + ty * 4 + i) * N_EXP;
        #pragma unroll
        for (int j = 0; j < 8; ++j) logits[row + tx + 32 * j] = acc[i][j];
    }
}

__global__ __launch_bounds__(256) void topk_only(
    const float* __restrict__ logits,
    float* __restrict__ out_idx, float* __restrict__ out_w)
{
    const int token = blockIdx.x * 4 + (threadIdx.x >> 6);
    const int lane  = threadIdx.x & 63;
    const float4 x = *(const float4*)(logits + (size_t)token * N_EXP + lane * 4);
    float sc[4];
    sc[0] = 1.0f / (1.0f + expf(-x.x)); sc[1] = 1.0f / (1.0f + expf(-x.y));
    sc[2] = 1.0f / (1.0f + expf(-x.z)); sc[3] = 1.0f / (1.0f + expf(-x.w));
    float v1 = -1.0f, v2 = -1.0f; int i1 = 0, i2 = 0;
    #pragma unroll
    for (int j = 0; j < 4; ++j) {
        const int idx = lane * 4 + j;
        if (sc[j] > v1)      { v2 = v1; i2 = i1; v1 = sc[j]; i1 = idx; }
        else if (sc[j] > v2) { v2 = sc[j]; i2 = idx; }
    }
    #pragma unroll
    for (int offx = 1; offx < 16; offx <<= 1) {
        const float ov1 = __shfl_xor(v1, offx); const int oi1 = __shfl_xor(i1, offx);
        const float ov2 = __shfl_xor(v2, offx); const int oi2 = __shfl_xor(i2, offx);
        const bool o1_beats_m1 = (ov1 > v1) || (ov1 == v1 && oi1 < i1);
        if (o1_beats_m1) {
            const bool m1_beats_o2 = (v1 > ov2) || (v1 == ov2 && i1 < oi2);
            const float nv2 = m1_beats_o2 ? v1 : ov2;
            const int   ni2 = m1_beats_o2 ? i1 : oi2;
            v1 = ov1; i1 = oi1; v2 = nv2; i2 = ni2;
        } else {
            const bool o1_beats_m2 = (ov1 > v2) || (ov1 == v2 && oi1 < i2);
            v2 = o1_beats_m2 ? ov1 : v2; i2 = o1_beats_m2 ? oi1 : i2;
        }
    }
    float sum = 0.0f;
    #pragma unroll
    for (int g = 0; g < 4; ++g) sum += __shfl(v1, g * 16) + __shfl(v2, g * 16);
    const int src = ((lane >> 1) & 3) * 16;
    const float mv1 = __shfl(v1, src), mv2 = __shfl(v2, src);
    const int   mi1 = __shfl(i1, src), mi2 = __shfl(i2, src);
    if (lane < 8) {
        const float myv = (lane & 1) ? mv2 : mv1;
        const int   myi = (lane & 1) ? mi2 : mi1;
        out_idx[(size_t)token * 8 + lane] = (float)myi;
        out_w  [(size_t)token * 8 + lane] = myv * (2.5f / (sum + 1e-10f));
    }
}

extern "C" void kernel_launch(void* const* d_in, const int* in_sizes, int n_in,
                              void* d_out, int out_size, void* d_ws, size_t ws_size,
                              hipStream_t stream) {
    const float* H = (const float*)d_in[0];   // hidden_states [8192, 4096]
    const float* W = (const float*)d_in[1];   // gate_w        [256, 4096]

    float* out     = (float*)d_out;
    float* out_idx = out;                           // 8192*8
    float* out_w   = out + (size_t)N_TOKENS * 8;    // 8192*8
    float* logits  = out + (size_t)N_TOKENS * 16;   // 8192*256

    if (ws_size >= WS_NEED) {
        unsigned short* wsB = (unsigned short*)d_ws;
        static bool attr_done = []() {
            hipFuncSetAttribute((const void*)gate_fused,
                                hipFuncAttributeMaxDynamicSharedMemorySize,
                                (int)LDS_BYTES);
            return true;
        }();
        (void)attr_done;
        convert_w<<<dim3(NC * 4), dim3(256), 0, stream>>>(W, wsB);
        gate_fused<<<dim3(N_TOKENS / BM), dim3(256), LDS_BYTES, stream>>>(
            H, wsB, logits, out_idx, out_w);
    } else {
        gate_gemm_f32<<<dim3(N_TOKENS / FBM), dim3(256), 0, stream>>>(H, W, logits);
        topk_only<<<dim3(N_TOKENS / 4), dim3(256), 0, stream>>>(logits, out_idx, out_w);
    }
}